// Round 30
// baseline (147.789 us; speedup 1.0000x reference)
//
#include <hip/hip_runtime.h>
#include <math.h>

#define B_    4
#define C_    256
#define N_    2304      // 48*48 tokens
#define H_    8
#define DH_   64
#define IN_   512       // heads*dim_head
#define ROWS_ 9216      // B_*N_
#define NHALF 1152      // KV split size (2-way)

typedef __attribute__((ext_vector_type(8))) short short8;
typedef __attribute__((ext_vector_type(4))) float f32x4;
typedef __attribute__((ext_vector_type(16))) float f32x16;

__device__ __forceinline__ unsigned short f2bf(float f) {
    unsigned int u = __float_as_uint(f);
    u += 0x7fffu + ((u >> 16) & 1u);    // round-to-nearest-even
    return (unsigned short)(u >> 16);
}

__device__ __forceinline__ float bf2f(unsigned short u) {
    return __uint_as_float(((unsigned)u) << 16);
}

// bare HW 2^x (args bounded in our use); compiler-known TRANS op.
__device__ __forceinline__ float fexp2(float x) {
    return __builtin_amdgcn_exp2f(x);
}

// tanh-form GELU on bare HW ops: x * sigmoid(1.5958(x+0.044715x^3)).
__device__ __forceinline__ float gelu_fast(float x) {
    float x2 = x * x;
    float u  = x * fmaf(0.044715f, x2, 1.0f);
    float e  = fexp2(-2.3022082f * u);          // exp(-1.5957691*u)
    return x * __builtin_amdgcn_rcpf(1.0f + e); // x * sigmoid
}

// pack two f32 -> one u32 of 2 bf16 (RNE), single instruction
__device__ __forceinline__ unsigned cvtpk(float lo, float hi) {
    unsigned r;
    asm("v_cvt_pk_bf16_f32 %0, %1, %2" : "=v"(r) : "v"(lo), "v"(hi));
    return r;
}

// async global->LDS, 16B per lane: LDS dest = lds base + lane*16 (HW).
__device__ __forceinline__ void gload_lds16(const void* g, void* l) {
    __builtin_amdgcn_global_load_lds(
        (const __attribute__((address_space(1))) unsigned int*)g,
        (__attribute__((address_space(3))) unsigned int*)l, 16, 0, 0);
}

// swizzled fragment pointer (GEMM): rows of 64 shorts (8 chunks of 16B),
// chunk c of row r stored at c^(r&7).
__device__ __forceinline__ const short8* frg(const short* base, int row, int chunk) {
    return (const short8*)(base + (row << 6) + (((chunk) ^ (row & 7)) << 3));
}

// 2-level swizzle (attention, 32-row groups): c ^ (r&7) ^ ((r>>3)&3)
__device__ __forceinline__ int swz2(int row) {
    return (row & 7) ^ ((row >> 3) & 3);
}
__device__ __forceinline__ const short8* frg2(const short* base, int row, int chunk) {
    return (const short8*)(base + (row << 6) + (((chunk) ^ swz2(row)) << 3));
}

// ---------------------------------------------------------------------------
// FUSED pre-pass: blocks 0..1791 = weight prep (W[K][N] fp32 -> Wt[N][K]
// bf16; Wq scaled by 0.125*log2e); blocks 1792..2079 = x-transpose + LN1.
__global__ __launch_bounds__(256)
void k_pre(const float* __restrict__ Wq, const float* __restrict__ Wk,
           const float* __restrict__ Wv, const float* __restrict__ Wo,
           const float* __restrict__ Wf1, const float* __restrict__ Wf2,
           const float* __restrict__ Wp,
           unsigned short* Wqh, unsigned short* Wkh, unsigned short* Wvh,
           unsigned short* Woh, unsigned short* Wf1h, unsigned short* Wf2h,
           unsigned short* Wph,
           const float* __restrict__ x, float* __restrict__ T,
           unsigned short* __restrict__ TNh,
           const float* __restrict__ g1, const float* __restrict__ b1) {
    __shared__ float tile[32][257];
    int bid = blockIdx.x;
    int tid = threadIdx.x;
    if (bid < 1792) {
        // ---- weight prep ----
        int wz = bid >> 8;             // 0..6
        int rem = bid & 255;
        int nBase = (rem & 15) * 32;   // dst row (= src col)
        int kBase = (rem >> 4) * 32;   // dst col (= src row)
        const float* src; unsigned short* dst; int K, N;
        switch (wz) {
            case 0: src = Wq;  dst = Wqh;  K = 256; N = 512; break;
            case 1: src = Wk;  dst = Wkh;  K = 256; N = 512; break;
            case 2: src = Wv;  dst = Wvh;  K = 256; N = 512; break;
            case 3: src = Wo;  dst = Woh;  K = 512; N = 256; break;
            case 4: src = Wf1; dst = Wf1h; K = 256; N = 512; break;
            case 5: src = Wf2; dst = Wf2h; K = 512; N = 256; break;
            default: src = Wp; dst = Wph;  K = 256; N = 256; break;
        }
        if (nBase >= N || kBase >= K) return;
        float scl = (wz == 0) ? 0.18033688f : 1.0f;
        int tx = tid & 31, ty = tid >> 5;
        #pragma unroll
        for (int i = 0; i < 32; i += 8)
            tile[ty + i][tx] = src[(size_t)(kBase + ty + i) * N + nBase + tx];
        __syncthreads();
        #pragma unroll
        for (int i = 0; i < 32; i += 8)
            dst[(size_t)(nBase + ty + i) * K + kBase + tx] = f2bf(tile[tx][ty + i] * scl);
    } else {
        // ---- x transpose + LayerNorm1 ----
        int idx = bid - 1792;
        int bb = idx / 72;
        int nBase = (idx - bb * 72) * 32;
        int tx = tid & 31;          // n within tile
        int tg = tid >> 5;          // 0..7 -> c-group
        const float* xp = x + (size_t)bb * C_ * N_ + nBase + tx;
        #pragma unroll
        for (int i = 0; i < 32; ++i) {
            int c = tg * 32 + i;
            tile[tx][c] = xp[(size_t)c * N_];
        }
        __syncthreads();
        int w = tid >> 6, lane = tid & 63;
        float g0 = g1[lane], ga = g1[lane + 64], gb2 = g1[lane + 128], gc = g1[lane + 192];
        float b0 = b1[lane], ba = b1[lane + 64], bb2 = b1[lane + 128], bc = b1[lane + 192];
        #pragma unroll
        for (int r8 = 0; r8 < 8; ++r8) {
            int row = w * 8 + r8;
            float v0 = tile[row][lane],       v1 = tile[row][lane + 64];
            float v2 = tile[row][lane + 128], v3 = tile[row][lane + 192];
            float s = v0 + v1 + v2 + v3;
            #pragma unroll
            for (int m = 1; m < 64; m <<= 1) s += __shfl_xor(s, m);
            float mean = s * (1.0f / C_);
            float d0 = v0 - mean, d1 = v1 - mean, d2 = v2 - mean, d3 = v3 - mean;
            float s2 = d0 * d0 + d1 * d1 + d2 * d2 + d3 * d3;
            #pragma unroll
            for (int m = 1; m < 64; m <<= 1) s2 += __shfl_xor(s2, m);
            float rs = rsqrtf(s2 * (1.0f / C_) + 1e-5f);
            size_t o = (size_t)(bb * N_ + nBase + row) * C_ + lane;
            T[o]       = v0; T[o + 64]  = v1; T[o + 128] = v2; T[o + 192] = v3;
            TNh[o]       = f2bf(d0 * rs * g0 + b0);
            TNh[o + 64]  = f2bf(d1 * rs * ga + ba);
            TNh[o + 128] = f2bf(d2 * rs * gb2 + bb2);
            TNh[o + 192] = f2bf(d3 * rs * gc + bc);
        }
    }
}

// ---------------------------------------------------------------------------
// row LayerNorm over C_=256, bf16 output: one wave per row, 4 floats/lane
__global__ __launch_bounds__(256)
void k_layernorm_bf16(const float* __restrict__ in, unsigned short* __restrict__ out,
                      const float* __restrict__ g, const float* __restrict__ b) {
    int wv = threadIdx.x >> 6;
    int lane = threadIdx.x & 63;
    int row = blockIdx.x * 4 + wv;
    float4 v = ((const float4*)(in + (size_t)row * C_))[lane];
    float s = v.x + v.y + v.z + v.w;
    #pragma unroll
    for (int m = 1; m < 64; m <<= 1) s += __shfl_xor(s, m);
    float mean = s * (1.0f / C_);
    float dx = v.x - mean, dy = v.y - mean, dz = v.z - mean, dw = v.w - mean;
    float s2 = dx * dx + dy * dy + dz * dz + dw * dw;
    #pragma unroll
    for (int m = 1; m < 64; m <<= 1) s2 += __shfl_xor(s2, m);
    float rs = rsqrtf(s2 * (1.0f / C_) + 1e-5f);
    float4 gv = ((const float4*)g)[lane];
    float4 bv = ((const float4*)b)[lane];
    ushort4 o;
    o.x = f2bf(dx * rs * gv.x + bv.x);
    o.y = f2bf(dy * rs * gv.y + bv.y);
    o.z = f2bf(dz * rs * gv.z + bv.z);
    o.w = f2bf(dw * rs * gv.w + bv.w);
    *(ushort4*)(out + (size_t)row * C_ + lane * 4) = o;
}

// ---------------------------------------------------------------------------
// Small-tile MFMA GEMM: 64x64 tile, BK=64, 4 waves (2x2), 32x32 per wave.
// EP: 2 fp32 +bias[br]+Res | 3 bf16 gelu(+bias[br]) | 4 bf16 +bias[br]+Res |
//     5 fp32 out[(bb*256+ar)*2304+n]+bias[ar]+Res[same]
template <int EP>
__global__ __launch_bounds__(256)
void k_gemm64(const short* __restrict__ A, const short* __restrict__ Bt,
              void* __restrict__ Out, const float* __restrict__ bias,
              const float* __restrict__ Res, int M, int N, int K) {
    __shared__ __align__(16) short As[64 * 64];
    __shared__ __align__(16) short Bs[64 * 64];
    int tid = threadIdx.x;
    int w = tid >> 6;
    int lane = tid & 63;
    int l15 = lane & 15;
    int lg = lane >> 4;
    int wr = w >> 1, wc = w & 1;
    int rowBase = blockIdx.y * 64;
    int colBase = blockIdx.x * 64;

    f32x4 acc[2][2];
    #pragma unroll
    for (int m = 0; m < 2; ++m)
        #pragma unroll
        for (int n = 0; n < 2; ++n) acc[m][n] = (f32x4){0.f, 0.f, 0.f, 0.f};

    for (int k0 = 0; k0 < K; k0 += 64) {
        __syncthreads();
        #pragma unroll
        for (int a = 0; a < 2; ++a) {
            int rr = (w << 4) + (a << 3) + (lane >> 3);
            int cc = (lane & 7) ^ (lane >> 3);     // rr&7 == lane>>3
            gload_lds16(A + (size_t)(rowBase + rr) * K + k0 + cc * 8,
                        As + (((w << 4) + (a << 3)) << 6));
            gload_lds16(Bt + (size_t)(colBase + rr) * K + k0 + cc * 8,
                        Bs + (((w << 4) + (a << 3)) << 6));
        }
        asm volatile("s_waitcnt vmcnt(0)" ::: "memory");
        __syncthreads();
        short8 af[2][2], bf[2][2];
        #pragma unroll
        for (int m = 0; m < 2; ++m) {
            af[m][0] = *frg(As, wr * 32 + m * 16 + l15, lg);
            af[m][1] = *frg(As, wr * 32 + m * 16 + l15, 4 + lg);
        }
        #pragma unroll
        for (int n = 0; n < 2; ++n) {
            bf[n][0] = *frg(Bs, wc * 32 + n * 16 + l15, lg);
            bf[n][1] = *frg(Bs, wc * 32 + n * 16 + l15, 4 + lg);
        }
        #pragma unroll
        for (int m = 0; m < 2; ++m)
            #pragma unroll
            for (int n = 0; n < 2; ++n) {
                acc[m][n] = __builtin_amdgcn_mfma_f32_16x16x32_bf16(af[m][0], bf[n][0], acc[m][n], 0, 0, 0);
                acc[m][n] = __builtin_amdgcn_mfma_f32_16x16x32_bf16(af[m][1], bf[n][1], acc[m][n], 0, 0, 0);
            }
    }

    int arB = rowBase + wr * 32;
    int brB = colBase + wc * 32;
    int bb = 0;
    if (EP == 5) bb = brB / N_;   // 64-col tiles never straddle batch
    #pragma unroll
    for (int m = 0; m < 2; ++m) {
        #pragma unroll
        for (int i = 0; i < 4; ++i) {
            int ar = arB + m * 16 + lg * 4 + i;
            #pragma unroll
            for (int n = 0; n < 2; ++n) {
                int br = brB + n * 16 + l15;
                float v = acc[m][n][i];
                if constexpr (EP == 2) {
                    size_t o = (size_t)ar * N + br;
                    ((float*)Out)[o] = v + bias[br] + Res[o];
                } else if constexpr (EP == 3) {
                    ((unsigned short*)Out)[(size_t)ar * N + br] = f2bf(gelu_fast(v + bias[br]));
                } else if constexpr (EP == 4) {
                    size_t o = (size_t)ar * N + br;
                    ((unsigned short*)Out)[o] = f2bf(v + bias[br] + Res[o]);
                } else {
                    size_t o = ((size_t)(bb * C_) + ar) * N_ + (br - bb * N_);
                    ((float*)Out)[o] = v + bias[ar] + Res[o];
                }
            }
        }
    }
}

// ---------------------------------------------------------------------------
// Fused QKV GEMM, 64x64 tiles, one dispatch of 3456 blocks (1D).
// z = bid/1152: 0 -> Qb, 1 -> Kb (A=TNh, Bt=W, [9216 x 512]);
// 2 -> Vt (A=Wvh [512 rows], Bt=TNh [9216 cols], transposed store).
__global__ __launch_bounds__(256)
void k_gemm_qkv(const short* __restrict__ TNh, const short* __restrict__ Wqh,
                const short* __restrict__ Wkh, const short* __restrict__ Wvh,
                unsigned short* __restrict__ Qb, unsigned short* __restrict__ Kb,
                unsigned short* __restrict__ Vt) {
    __shared__ __align__(16) short As[64 * 64];
    __shared__ __align__(16) short Bs[64 * 64];
    int bid = blockIdx.x;
    int z = bid / 1152;
    int rem = bid - z * 1152;
    int tid = threadIdx.x;
    int w = tid >> 6;
    int lane = tid & 63;
    int l15 = lane & 15;
    int lg = lane >> 4;
    int wr = w >> 1, wc = w & 1;
    const short *A, *Bt;
    int rowBase, colBase;
    if (z < 2) {
        A = TNh; Bt = z ? Wkh : Wqh;
        colBase = (rem & 7) * 64;        // 8 col tiles (512)
        rowBase = (rem >> 3) * 64;       // 144 row tiles (9216)
    } else {
        A = Wvh; Bt = TNh;
        colBase = (rem % 144) * 64;      // 144 col tiles (9216)
        rowBase = (rem / 144) * 64;      // 8 row tiles (512)
    }
    const int K = C_;

    f32x4 acc[2][2];
    #pragma unroll
    for (int m = 0; m < 2; ++m)
        #pragma unroll
        for (int n = 0; n < 2; ++n) acc[m][n] = (f32x4){0.f, 0.f, 0.f, 0.f};

    for (int k0 = 0; k0 < K; k0 += 64) {
        __syncthreads();
        #pragma unroll
        for (int a = 0; a < 2; ++a) {
            int rr = (w << 4) + (a << 3) + (lane >> 3);
            int cc = (lane & 7) ^ (lane >> 3);
            gload_lds16(A + (size_t)(rowBase + rr) * K + k0 + cc * 8,
                        As + (((w << 4) + (a << 3)) << 6));
            gload_lds16(Bt + (size_t)(colBase + rr) * K + k0 + cc * 8,
                        Bs + (((w << 4) + (a << 3)) << 6));
        }
        asm volatile("s_waitcnt vmcnt(0)" ::: "memory");
        __syncthreads();
        short8 af[2][2], bf[2][2];
        #pragma unroll
        for (int m = 0; m < 2; ++m) {
            af[m][0] = *frg(As, wr * 32 + m * 16 + l15, lg);
            af[m][1] = *frg(As, wr * 32 + m * 16 + l15, 4 + lg);
        }
        #pragma unroll
        for (int n = 0; n < 2; ++n) {
            bf[n][0] = *frg(Bs, wc * 32 + n * 16 + l15, lg);
            bf[n][1] = *frg(Bs, wc * 32 + n * 16 + l15, 4 + lg);
        }
        #pragma unroll
        for (int m = 0; m < 2; ++m)
            #pragma unroll
            for (int n = 0; n < 2; ++n) {
                acc[m][n] = __builtin_amdgcn_mfma_f32_16x16x32_bf16(af[m][0], bf[n][0], acc[m][n], 0, 0, 0);
                acc[m][n] = __builtin_amdgcn_mfma_f32_16x16x32_bf16(af[m][1], bf[n][1], acc[m][n], 0, 0, 0);
            }
    }

    int arB = rowBase + wr * 32;
    int brB = colBase + wc * 32;
    if (z < 2) {
        unsigned short* Out = z ? Kb : Qb;
        #pragma unroll
        for (int m = 0; m < 2; ++m)
            #pragma unroll
            for (int i = 0; i < 4; ++i) {
                int ar = arB + m * 16 + lg * 4 + i;
                #pragma unroll
                for (int n = 0; n < 2; ++n)
                    Out[(size_t)ar * IN_ + brB + n * 16 + l15] = f2bf(acc[m][n][i]);
            }
    } else {
        int bb = brB / N_;
        #pragma unroll
        for (int m = 0; m < 2; ++m)
            #pragma unroll
            for (int i = 0; i < 4; ++i) {
                int ar = arB + m * 16 + lg * 4 + i;
                #pragma unroll
                for (int n = 0; n < 2; ++n) {
                    int br = brB + n * 16 + l15;
                    Vt[((size_t)(bb * IN_) + ar) * N_ + (br - bb * N_)] = f2bf(acc[m][n][i]);
                }
            }
    }
}

// ---------------------------------------------------------------------------
// MFMA flash attention, 2-way KV split, in-register P, shift-free softmax,
// l via ones-MFMA, gload_lds dbuf staging.
// ROUND 30: TWO q-tiles per block (256 q-rows; wave = 2x32 rows). Shared
// fragment reads: each kf feeds 2 MFMAs (stvA,stvB), each vf/vg feeds 6.
// 40 MFMAs per barrier (2x), LDS reads per unit compute halved, and two
// independent dep-chains per wave (ILP replaces TLP). (256,2) bounds for
// the doubled accumulator set (~200 regs peak, no spill).
__global__ __launch_bounds__(256, 2)
void k_flash_mfma(const short* __restrict__ Qb, const short* __restrict__ Kb,
                  const short* __restrict__ Vt,
                  unsigned short* O0, unsigned short* O1,
                  float* __restrict__ Lsum) {
    __shared__ __align__(16) short Ks[2][64 * 64];   // [kv][d] swizzled (swz2)
    __shared__ __align__(16) short Vs[2][64 * 64];   // [d][kv] swizzled (swz2)
    int tid = threadIdx.x;
    int lane = tid & 63;
    int l31 = lane & 31;
    int h5 = lane >> 5;         // 0/1
    int w = tid >> 6;

    // 576 blocks: logical = xcd*72 + idx; pair = logical/9 ((half<<5)|bh),
    // qi = logical%9 -> qBase = qi*256 (two 128-row q-tiles A/B).
    int logical = (blockIdx.x & 7) * 72 + (blockIdx.x >> 3);
    int pair = logical / 9;
    int qi = logical - pair * 9;
    int bh = pair & 31;
    int half = pair >> 5;
    int bb = bh >> 3, h = bh & 7;
    int qBase = qi * 256;
    int h0 = half * NHALF;

    const short* QpA = Qb + ((size_t)bb * N_ + qBase + w * 32) * IN_ + h * DH_;
    const short* QpB = QpA + (size_t)128 * IN_;
    const short* Kp = Kb + (size_t)bb * N_ * IN_ + h * DH_;
    const short* Vp = Vt + ((size_t)bb * IN_ + h * DH_) * N_;

    // Q fragments (B-operand, col q = l31, k = kk*16 + h5*8 + j), from global
    short8 qfA[4], qfB[4];
    #pragma unroll
    for (int kk = 0; kk < 4; ++kk) {
        qfA[kk] = *(const short8*)(QpA + (size_t)l31 * IN_ + kk * 16 + h5 * 8);
        qfB[kk] = *(const short8*)(QpB + (size_t)l31 * IN_ + kk * 16 + h5 * 8);
    }

    // bf16 ones fragment for the l-accumulating MFMA
    short8 ones;
    #pragma unroll
    for (int j = 0; j < 8; ++j) ones[j] = (short)0x3F80;

    auto STAGE = [&](int buf, int kt2) {
        #pragma unroll
        for (int j = 0; j < 2; ++j) {
            int br = (w << 4) + (j << 3);
            int rr = br + (lane >> 3);
            int cc = (lane & 7) ^ (lane >> 3) ^ ((2 * w + j) & 3);
            gload_lds16(Kp + (size_t)(kt2 + rr) * IN_ + cc * 8, &Ks[buf][br << 6]);
            gload_lds16(Vp + (size_t)rr * N_ + kt2 + cc * 8, &Vs[buf][br << 6]);
        }
    };

    // softmax+pack for one subtile's stv -> two A-fragments (pa_lo, pa_hi)
    auto SMPACK = [&](const f32x16& stv, short8& paLo, short8& paHi) {
        unsigned u[8];
        #pragma unroll
        for (int q = 0; q < 4; ++q) {
            u[2 * q]     = cvtpk(fexp2(stv[4 * q + 0]), fexp2(stv[4 * q + 1]));
            u[2 * q + 1] = cvtpk(fexp2(stv[4 * q + 2]), fexp2(stv[4 * q + 3]));
        }
        asm volatile("v_permlane32_swap_b32 %0, %1" : "+v"(u[0]), "+v"(u[2]));
        asm volatile("v_permlane32_swap_b32 %0, %1" : "+v"(u[1]), "+v"(u[3]));
        asm volatile("v_permlane32_swap_b32 %0, %1" : "+v"(u[4]), "+v"(u[6]));
        asm volatile("v_permlane32_swap_b32 %0, %1" : "+v"(u[5]), "+v"(u[7]));
        union { unsigned uu[4]; short8 s8; } c0, c1;
        c0.uu[0] = u[0]; c0.uu[1] = u[1]; c0.uu[2] = u[2]; c0.uu[3] = u[3];
        c1.uu[0] = u[4]; c1.uu[1] = u[5]; c1.uu[2] = u[6]; c1.uu[3] = u[7];
        paLo = c0.s8;
        paHi = c1.s8;
    };

    f32x16 oaccA0 = (f32x16)(0.0f), oaccA1 = (f32x16)(0.0f), laccA = (f32x16)(0.0f);
    f32x16 oaccB0 = (f32x16)(0.0f), oaccB1 = (f32x16)(0.0f), laccB = (f32x16)(0.0f);

    STAGE(0, h0);
    const int NT = NHALF / 64;   // 18 tiles
    for (int t = 0; t < NT; ++t) {
        asm volatile("s_waitcnt vmcnt(0)" ::: "memory");  // tile t landed
        __builtin_amdgcn_s_barrier();                     // all waves' loads in
        __builtin_amdgcn_sched_barrier(0);                // pin ds_reads after
        if (t + 1 < NT) STAGE((t + 1) & 1, h0 + (t + 1) * 64);  // fly over compute
        const short* Kc = Ks[t & 1];
        const short* Vc = Vs[t & 1];

        // --- QK^T: both q-tiles share each kf read (2 MFMAs per ds_read) ---
        f32x16 stvA0 = (f32x16)(0.0f), stvB0 = (f32x16)(0.0f);
        f32x16 stvA1 = (f32x16)(0.0f), stvB1 = (f32x16)(0.0f);
        __builtin_amdgcn_s_setprio(1);
        #pragma unroll
        for (int kk = 0; kk < 4; ++kk) {
            short8 kf = *frg2(Kc, l31, kk * 2 + h5);
            stvA0 = __builtin_amdgcn_mfma_f32_32x32x16_bf16(kf, qfA[kk], stvA0, 0, 0, 0);
            stvB0 = __builtin_amdgcn_mfma_f32_32x32x16_bf16(kf, qfB[kk], stvB0, 0, 0, 0);
        }
        #pragma unroll
        for (int kk = 0; kk < 4; ++kk) {
            short8 kf = *frg2(Kc, 32 + l31, kk * 2 + h5);
            stvA1 = __builtin_amdgcn_mfma_f32_32x32x16_bf16(kf, qfA[kk], stvA1, 0, 0, 0);
            stvB1 = __builtin_amdgcn_mfma_f32_32x32x16_bf16(kf, qfB[kk], stvB1, 0, 0, 0);
        }
        __builtin_amdgcn_s_setprio(0);

        // --- softmax for all 4 subtiles (VALU/TRANS under QK MFMA drain) ---
        short8 paA[4], paB[4];
        SMPACK(stvA0, paA[0], paA[1]);
        SMPACK(stvB0, paB[0], paB[1]);
        SMPACK(stvA1, paA[2], paA[3]);
        SMPACK(stvB1, paB[2], paB[3]);

        // --- PV: each vf/vg read feeds 6 MFMAs (A + B) ---
        __builtin_amdgcn_s_setprio(1);
        #pragma unroll
        for (int kk = 0; kk < 4; ++kk) {
            short8 vf = *frg2(Vc, l31, kk * 2 + h5);
            short8 vg = *frg2(Vc, 32 + l31, kk * 2 + h5);
            laccA  = __builtin_amdgcn_mfma_f32_32x32x16_bf16(paA[kk], ones, laccA, 0, 0, 0);
            oaccA0 = __builtin_amdgcn_mfma_f32_32x32x16_bf16(paA[kk], vf, oaccA0, 0, 0, 0);
            oaccA1 = __builtin_amdgcn_mfma_f32_32x32x16_bf16(paA[kk], vg, oaccA1, 0, 0, 0);
            laccB  = __builtin_amdgcn_mfma_f32_32x32x16_bf16(paB[kk], ones, laccB, 0, 0, 0);
            oaccB0 = __builtin_amdgcn_mfma_f32_32x32x16_bf16(paB[kk], vf, oaccB0, 0, 0, 0);
            oaccB1 = __builtin_amdgcn_mfma_f32_32x32x16_bf16(paB[kk], vg, oaccB1, 0, 0, 0);
        }
        __builtin_amdgcn_s_setprio(0);
    }

    // store UNNORMALIZED bf16 partials; C/D row q = (reg&3)+8*(reg>>2)+4*h5
    unsigned short* OpH = (half == 0) ? O0 : O1;
    unsigned short* OpA = OpH + ((size_t)bb * N_ + qBase + w * 32) * IN_ + h * DH_;
    unsigned short* OpB = OpA + (size_t)128 * IN_;
    #pragma unroll
    for (int reg = 0; reg < 16; ++reg) {
        int q = (reg & 3) + 8 * (reg >> 2) + 4 * h5;
        OpA[(size_t)q * IN_ + l31]      = f2bf(oaccA0[reg]);
        OpA[(size_t)q * IN_ + 32 + l31] = f2bf(oaccA1[reg]);
        OpB[(size_t)q * IN_ + l31]      = f2bf(oaccB0[reg]);
        OpB[(size_t)q * IN_ + 32 + l31] = f2bf(oaccB1[reg]);
    }
    if (l31 == 0) {
        float* LpA = Lsum + (((size_t)half * B_ + bb) * H_ + h) * N_ + qBase + w * 32;
        float* LpB = LpA + 128;
        #pragma unroll
        for (int reg = 0; reg < 16; ++reg) {
            int q = (reg & 3) + 8 * (reg >> 2) + 4 * h5;
            LpA[q] = laccA[reg];
            LpB[q] = laccB[reg];
        }
    }
}

// ---------------------------------------------------------------------------
// Combine the 2 KV-half partials: O = (O0+O1) / (l0+l1).
// NOTE: Ob aliases p1's buffer — each thread reads both partials for its
// row/lanes before writing the identical addresses, so this is race-free.
__global__ __launch_bounds__(256)
void k_combine(const unsigned short* p0, const unsigned short* p1,
               const float* __restrict__ Lsum, unsigned short* Ob) {
    int wv = threadIdx.x >> 6;
    int lane = threadIdx.x & 63;
    int row = blockIdx.x * 4 + wv;      // bb*N_ + n
    int bb = row / N_;
    int n = row - bb * N_;
    int hh = lane >> 3;
    float l0 = Lsum[(((size_t)0 * B_ + bb) * H_ + hh) * N_ + n];
    float l1 = Lsum[(((size_t)1 * B_ + bb) * H_ + hh) * N_ + n];
    float inv = 1.0f / (l0 + l1);
    size_t off = (size_t)row * IN_ + lane * 8;
    short8 a0 = *(const short8*)(p0 + off);
    short8 a1 = *(const short8*)(p1 + off);
    unsigned short o[8];
    #pragma unroll
    for (int j = 0; j < 8; ++j)
        o[j] = f2bf((bf2f((unsigned short)a0[j]) + bf2f((unsigned short)a1[j])) * inv);
    *(uint4*)(Ob + off) = *(uint4*)o;
}

// ---------------------------------------------------------------------------
extern "C" void kernel_launch(void* const* d_in, const int* in_sizes, int n_in,
                              void* d_out, int out_size, void* d_ws, size_t ws_size,
                              hipStream_t stream) {
    (void)in_sizes; (void)n_in; (void)out_size; (void)ws_size;
    const float* x   = (const float*)d_in[0];
    const float* Wq  = (const float*)d_in[1];
    const float* Wk  = (const float*)d_in[2];
    const float* Wv  = (const float*)d_in[3];
    const float* Wo  = (const float*)d_in[4];
    const float* bo  = (const float*)d_in[5];
    const float* g1  = (const float*)d_in[6];
    const float* b1  = (const float*)d_in[7];
    const float* g2  = (const float*)d_in[8];
    const float* b2  = (const float*)d_in[9];
    const float* Wf1 = (const float*)d_in[10];
    const float* bf1 = (const float*)d_in[11];
    const float* Wf2 = (const float*)d_in[12];
    const float* bf2 = (const float*)d_in[13];
    const float* Wp  = (const float*)d_in[14];
    const float* bp  = (const float*)d_in[15];
    float* out = (float*)d_out;
    float* ws  = (float*)d_ws;

    float* T    = ws;                                  // [9216,256] f32
    float* T2   = ws + 2359296;                        // [9216,256] f32
    unsigned short* TNh = (unsigned short*)(ws + 4718592);   // [9216,256] bf16
    short* Qb   = (short*)(ws + 5898240);              // [9216,512] bf16
    short* Kb   = (short*)(ws + 8257536);              // [9216,512] bf16
    short* Vt   = (short*)(ws + 10616832);             // [4,512,2304] bf16
    unsigned short* Obh = (unsigned short*)(ws + 12976128); // [9216,512] bf16 (= partial 1)
    short* F    = (short*)(ws + 15335424);             // [9216,512] bf16
    short* T3h  = (short*)(ws + 17694720);             // [9216,256] bf16
    unsigned short* Wqh  = (unsigned short*)(ws + 18874368);
    unsigned short* Wkh  = (unsigned short*)(ws + 18939904);
    unsigned short* Wvh  = (unsigned short*)(ws + 19005440);
    unsigned short* Woh  = (unsigned short*)(ws + 19070976);
    unsigned short* Wf1h = (unsigned short*)(ws + 19136512);
    unsigned short* Wf2h = (unsigned short*)(ws + 19202048);
    unsigned short* Wph  = (unsigned short*)(ws + 19267584);
    unsigned short* Op0  = (unsigned short*)(ws + 19398656); // [9216,512] bf16
    unsigned short* Op1  = Obh;                               // aliased (safe)
    float* Lsum = ws + 24117248;                       // [2,4,8,2304] f32

    k_pre<<<dim3(2080), 256, 0, stream>>>(Wq, Wk, Wv, Wo, Wf1, Wf2, Wp,
                                          Wqh, Wkh, Wvh, Woh, Wf1h, Wf2h, Wph,
                                          x, T, TNh, g1, b1);
    k_gemm_qkv<<<dim3(3456), 256, 0, stream>>>((const short*)TNh, (const short*)Wqh,
                                               (const short*)Wkh, (const short*)Wvh,
                                               (unsigned short*)Qb, (unsigned short*)Kb,
                                               (unsigned short*)Vt);
    k_flash_mfma<<<dim3(576), 256, 0, stream>>>(Qb, Kb, Vt, Op0, Op1, Lsum);
    k_combine<<<2304, 256, 0, stream>>>(Op0, Op1, Lsum, Obh);
    k_gemm64<2><<<dim3(4, 144), 256, 0, stream>>>((const short*)Obh, (const short*)Woh, T2, bo, T, ROWS_, C_, IN_);
    k_layernorm_bf16<<<2304, 256, 0, stream>>>(T2, TNh, g2, b2);
    k_gemm64<3><<<dim3(8, 144), 256, 0, stream>>>((const short*)TNh, (const short*)Wf1h, F, bf1, nullptr, ROWS_, IN_, C_);
    k_gemm64<4><<<dim3(4, 144), 256, 0, stream>>>((const short*)F, (const short*)Wf2h, T3h, bf2, T2, ROWS_, C_, IN_);
    k_gemm64<5><<<dim3(144, 4), 256, 0, stream>>>((const short*)Wph, (const short*)T3h, out, bp, x, C_, ROWS_, C_);
}

// Round 31
// 139.228 us; speedup vs baseline: 1.0615x; 1.0615x over previous
//
#include <hip/hip_runtime.h>
#include <math.h>

#define B_    4
#define C_    256
#define N_    2304      // 48*48 tokens
#define H_    8
#define DH_   64
#define IN_   512       // heads*dim_head
#define ROWS_ 9216      // B_*N_
#define NHALF 1152      // KV split size (2-way)

typedef __attribute__((ext_vector_type(8))) short short8;
typedef __attribute__((ext_vector_type(4))) float f32x4;
typedef __attribute__((ext_vector_type(16))) float f32x16;

__device__ __forceinline__ unsigned short f2bf(float f) {
    unsigned int u = __float_as_uint(f);
    u += 0x7fffu + ((u >> 16) & 1u);    // round-to-nearest-even
    return (unsigned short)(u >> 16);
}

__device__ __forceinline__ float bf2f(unsigned short u) {
    return __uint_as_float(((unsigned)u) << 16);
}

// bare HW 2^x (args bounded in our use); compiler-known TRANS op.
__device__ __forceinline__ float fexp2(float x) {
    return __builtin_amdgcn_exp2f(x);
}

// tanh-form GELU on bare HW ops: x * sigmoid(1.5958(x+0.044715x^3)).
__device__ __forceinline__ float gelu_fast(float x) {
    float x2 = x * x;
    float u  = x * fmaf(0.044715f, x2, 1.0f);
    float e  = fexp2(-2.3022082f * u);          // exp(-1.5957691*u)
    return x * __builtin_amdgcn_rcpf(1.0f + e); // x * sigmoid
}

// pack two f32 -> one u32 of 2 bf16 (RNE), single instruction
__device__ __forceinline__ unsigned cvtpk(float lo, float hi) {
    unsigned r;
    asm("v_cvt_pk_bf16_f32 %0, %1, %2" : "=v"(r) : "v"(lo), "v"(hi));
    return r;
}

// async global->LDS, 16B per lane: LDS dest = lds base + lane*16 (HW).
__device__ __forceinline__ void gload_lds16(const void* g, void* l) {
    __builtin_amdgcn_global_load_lds(
        (const __attribute__((address_space(1))) unsigned int*)g,
        (__attribute__((address_space(3))) unsigned int*)l, 16, 0, 0);
}

// swizzled fragment pointer (GEMM): rows of 64 shorts (8 chunks of 16B),
// chunk c of row r stored at c^(r&7).
__device__ __forceinline__ const short8* frg(const short* base, int row, int chunk) {
    return (const short8*)(base + (row << 6) + (((chunk) ^ (row & 7)) << 3));
}

// 2-level swizzle (attention, 32-row groups): c ^ (r&7) ^ ((r>>3)&3)
__device__ __forceinline__ int swz2(int row) {
    return (row & 7) ^ ((row >> 3) & 3);
}
__device__ __forceinline__ const short8* frg2(const short* base, int row, int chunk) {
    return (const short8*)(base + (row << 6) + (((chunk) ^ swz2(row)) << 3));
}

// ---------------------------------------------------------------------------
// FUSED pre-pass: blocks 0..1791 = weight prep (W[K][N] fp32 -> Wt[N][K]
// bf16; Wq scaled by 0.125*log2e); blocks 1792..2079 = x-transpose + LN1.
__global__ __launch_bounds__(256)
void k_pre(const float* __restrict__ Wq, const float* __restrict__ Wk,
           const float* __restrict__ Wv, const float* __restrict__ Wo,
           const float* __restrict__ Wf1, const float* __restrict__ Wf2,
           const float* __restrict__ Wp,
           unsigned short* Wqh, unsigned short* Wkh, unsigned short* Wvh,
           unsigned short* Woh, unsigned short* Wf1h, unsigned short* Wf2h,
           unsigned short* Wph,
           const float* __restrict__ x, float* __restrict__ T,
           unsigned short* __restrict__ TNh,
           const float* __restrict__ g1, const float* __restrict__ b1) {
    __shared__ float tile[32][257];
    int bid = blockIdx.x;
    int tid = threadIdx.x;
    if (bid < 1792) {
        // ---- weight prep ----
        int wz = bid >> 8;             // 0..6
        int rem = bid & 255;
        int nBase = (rem & 15) * 32;   // dst row (= src col)
        int kBase = (rem >> 4) * 32;   // dst col (= src row)
        const float* src; unsigned short* dst; int K, N;
        switch (wz) {
            case 0: src = Wq;  dst = Wqh;  K = 256; N = 512; break;
            case 1: src = Wk;  dst = Wkh;  K = 256; N = 512; break;
            case 2: src = Wv;  dst = Wvh;  K = 256; N = 512; break;
            case 3: src = Wo;  dst = Woh;  K = 512; N = 256; break;
            case 4: src = Wf1; dst = Wf1h; K = 256; N = 512; break;
            case 5: src = Wf2; dst = Wf2h; K = 512; N = 256; break;
            default: src = Wp; dst = Wph;  K = 256; N = 256; break;
        }
        if (nBase >= N || kBase >= K) return;
        float scl = (wz == 0) ? 0.18033688f : 1.0f;
        int tx = tid & 31, ty = tid >> 5;
        #pragma unroll
        for (int i = 0; i < 32; i += 8)
            tile[ty + i][tx] = src[(size_t)(kBase + ty + i) * N + nBase + tx];
        __syncthreads();
        #pragma unroll
        for (int i = 0; i < 32; i += 8)
            dst[(size_t)(nBase + ty + i) * K + kBase + tx] = f2bf(tile[tx][ty + i] * scl);
    } else {
        // ---- x transpose + LayerNorm1 ----
        int idx = bid - 1792;
        int bb = idx / 72;
        int nBase = (idx - bb * 72) * 32;
        int tx = tid & 31;          // n within tile
        int tg = tid >> 5;          // 0..7 -> c-group
        const float* xp = x + (size_t)bb * C_ * N_ + nBase + tx;
        #pragma unroll
        for (int i = 0; i < 32; ++i) {
            int c = tg * 32 + i;
            tile[tx][c] = xp[(size_t)c * N_];
        }
        __syncthreads();
        int w = tid >> 6, lane = tid & 63;
        float g0 = g1[lane], ga = g1[lane + 64], gb2 = g1[lane + 128], gc = g1[lane + 192];
        float b0 = b1[lane], ba = b1[lane + 64], bb2 = b1[lane + 128], bc = b1[lane + 192];
        #pragma unroll
        for (int r8 = 0; r8 < 8; ++r8) {
            int row = w * 8 + r8;
            float v0 = tile[row][lane],       v1 = tile[row][lane + 64];
            float v2 = tile[row][lane + 128], v3 = tile[row][lane + 192];
            float s = v0 + v1 + v2 + v3;
            #pragma unroll
            for (int m = 1; m < 64; m <<= 1) s += __shfl_xor(s, m);
            float mean = s * (1.0f / C_);
            float d0 = v0 - mean, d1 = v1 - mean, d2 = v2 - mean, d3 = v3 - mean;
            float s2 = d0 * d0 + d1 * d1 + d2 * d2 + d3 * d3;
            #pragma unroll
            for (int m = 1; m < 64; m <<= 1) s2 += __shfl_xor(s2, m);
            float rs = rsqrtf(s2 * (1.0f / C_) + 1e-5f);
            size_t o = (size_t)(bb * N_ + nBase + row) * C_ + lane;
            T[o]       = v0; T[o + 64]  = v1; T[o + 128] = v2; T[o + 192] = v3;
            TNh[o]       = f2bf(d0 * rs * g0 + b0);
            TNh[o + 64]  = f2bf(d1 * rs * ga + ba);
            TNh[o + 128] = f2bf(d2 * rs * gb2 + bb2);
            TNh[o + 192] = f2bf(d3 * rs * gc + bc);
        }
    }
}

// ---------------------------------------------------------------------------
// row LayerNorm over C_=256, bf16 output: one wave per row, 4 floats/lane
__global__ __launch_bounds__(256)
void k_layernorm_bf16(const float* __restrict__ in, unsigned short* __restrict__ out,
                      const float* __restrict__ g, const float* __restrict__ b) {
    int wv = threadIdx.x >> 6;
    int lane = threadIdx.x & 63;
    int row = blockIdx.x * 4 + wv;
    float4 v = ((const float4*)(in + (size_t)row * C_))[lane];
    float s = v.x + v.y + v.z + v.w;
    #pragma unroll
    for (int m = 1; m < 64; m <<= 1) s += __shfl_xor(s, m);
    float mean = s * (1.0f / C_);
    float dx = v.x - mean, dy = v.y - mean, dz = v.z - mean, dw = v.w - mean;
    float s2 = dx * dx + dy * dy + dz * dz + dw * dw;
    #pragma unroll
    for (int m = 1; m < 64; m <<= 1) s2 += __shfl_xor(s2, m);
    float rs = rsqrtf(s2 * (1.0f / C_) + 1e-5f);
    float4 gv = ((const float4*)g)[lane];
    float4 bv = ((const float4*)b)[lane];
    ushort4 o;
    o.x = f2bf(dx * rs * gv.x + bv.x);
    o.y = f2bf(dy * rs * gv.y + bv.y);
    o.z = f2bf(dz * rs * gv.z + bv.z);
    o.w = f2bf(dw * rs * gv.w + bv.w);
    *(ushort4*)(out + (size_t)row * C_ + lane * 4) = o;
}

// ---------------------------------------------------------------------------
// Small-tile MFMA GEMM: 64x64 tile, BK=64, 4 waves (2x2), 32x32 per wave.
// EP: 2 fp32 +bias[br]+Res | 3 bf16 gelu(+bias[br]) | 4 bf16 +bias[br]+Res |
//     5 fp32 out[(bb*256+ar)*2304+n]+bias[ar]+Res[same]
template <int EP>
__global__ __launch_bounds__(256)
void k_gemm64(const short* __restrict__ A, const short* __restrict__ Bt,
              void* __restrict__ Out, const float* __restrict__ bias,
              const float* __restrict__ Res, int M, int N, int K) {
    __shared__ __align__(16) short As[64 * 64];
    __shared__ __align__(16) short Bs[64 * 64];
    int tid = threadIdx.x;
    int w = tid >> 6;
    int lane = tid & 63;
    int l15 = lane & 15;
    int lg = lane >> 4;
    int wr = w >> 1, wc = w & 1;
    int rowBase = blockIdx.y * 64;
    int colBase = blockIdx.x * 64;

    f32x4 acc[2][2];
    #pragma unroll
    for (int m = 0; m < 2; ++m)
        #pragma unroll
        for (int n = 0; n < 2; ++n) acc[m][n] = (f32x4){0.f, 0.f, 0.f, 0.f};

    for (int k0 = 0; k0 < K; k0 += 64) {
        __syncthreads();
        #pragma unroll
        for (int a = 0; a < 2; ++a) {
            int rr = (w << 4) + (a << 3) + (lane >> 3);
            int cc = (lane & 7) ^ (lane >> 3);     // rr&7 == lane>>3
            gload_lds16(A + (size_t)(rowBase + rr) * K + k0 + cc * 8,
                        As + (((w << 4) + (a << 3)) << 6));
            gload_lds16(Bt + (size_t)(colBase + rr) * K + k0 + cc * 8,
                        Bs + (((w << 4) + (a << 3)) << 6));
        }
        asm volatile("s_waitcnt vmcnt(0)" ::: "memory");
        __syncthreads();
        short8 af[2][2], bf[2][2];
        #pragma unroll
        for (int m = 0; m < 2; ++m) {
            af[m][0] = *frg(As, wr * 32 + m * 16 + l15, lg);
            af[m][1] = *frg(As, wr * 32 + m * 16 + l15, 4 + lg);
        }
        #pragma unroll
        for (int n = 0; n < 2; ++n) {
            bf[n][0] = *frg(Bs, wc * 32 + n * 16 + l15, lg);
            bf[n][1] = *frg(Bs, wc * 32 + n * 16 + l15, 4 + lg);
        }
        #pragma unroll
        for (int m = 0; m < 2; ++m)
            #pragma unroll
            for (int n = 0; n < 2; ++n) {
                acc[m][n] = __builtin_amdgcn_mfma_f32_16x16x32_bf16(af[m][0], bf[n][0], acc[m][n], 0, 0, 0);
                acc[m][n] = __builtin_amdgcn_mfma_f32_16x16x32_bf16(af[m][1], bf[n][1], acc[m][n], 0, 0, 0);
            }
    }

    int arB = rowBase + wr * 32;
    int brB = colBase + wc * 32;
    int bb = 0;
    if (EP == 5) bb = brB / N_;   // 64-col tiles never straddle batch
    #pragma unroll
    for (int m = 0; m < 2; ++m) {
        #pragma unroll
        for (int i = 0; i < 4; ++i) {
            int ar = arB + m * 16 + lg * 4 + i;
            #pragma unroll
            for (int n = 0; n < 2; ++n) {
                int br = brB + n * 16 + l15;
                float v = acc[m][n][i];
                if constexpr (EP == 2) {
                    size_t o = (size_t)ar * N + br;
                    ((float*)Out)[o] = v + bias[br] + Res[o];
                } else if constexpr (EP == 3) {
                    ((unsigned short*)Out)[(size_t)ar * N + br] = f2bf(gelu_fast(v + bias[br]));
                } else if constexpr (EP == 4) {
                    size_t o = (size_t)ar * N + br;
                    ((unsigned short*)Out)[o] = f2bf(v + bias[br] + Res[o]);
                } else {
                    size_t o = ((size_t)(bb * C_) + ar) * N_ + (br - bb * N_);
                    ((float*)Out)[o] = v + bias[ar] + Res[o];
                }
            }
        }
    }
}

// ---------------------------------------------------------------------------
// Fused QKV GEMM, 64x64 tiles, one dispatch of 3456 blocks (1D).
// z = bid/1152: 0 -> Qb, 1 -> Kb (A=TNh, Bt=W, [9216 x 512]);
// 2 -> Vt (A=Wvh [512 rows], Bt=TNh [9216 cols], transposed store).
__global__ __launch_bounds__(256)
void k_gemm_qkv(const short* __restrict__ TNh, const short* __restrict__ Wqh,
                const short* __restrict__ Wkh, const short* __restrict__ Wvh,
                unsigned short* __restrict__ Qb, unsigned short* __restrict__ Kb,
                unsigned short* __restrict__ Vt) {
    __shared__ __align__(16) short As[64 * 64];
    __shared__ __align__(16) short Bs[64 * 64];
    int bid = blockIdx.x;
    int z = bid / 1152;
    int rem = bid - z * 1152;
    int tid = threadIdx.x;
    int w = tid >> 6;
    int lane = tid & 63;
    int l15 = lane & 15;
    int lg = lane >> 4;
    int wr = w >> 1, wc = w & 1;
    const short *A, *Bt;
    int rowBase, colBase;
    if (z < 2) {
        A = TNh; Bt = z ? Wkh : Wqh;
        colBase = (rem & 7) * 64;        // 8 col tiles (512)
        rowBase = (rem >> 3) * 64;       // 144 row tiles (9216)
    } else {
        A = Wvh; Bt = TNh;
        colBase = (rem % 144) * 64;      // 144 col tiles (9216)
        rowBase = (rem / 144) * 64;      // 8 row tiles (512)
    }
    const int K = C_;

    f32x4 acc[2][2];
    #pragma unroll
    for (int m = 0; m < 2; ++m)
        #pragma unroll
        for (int n = 0; n < 2; ++n) acc[m][n] = (f32x4){0.f, 0.f, 0.f, 0.f};

    for (int k0 = 0; k0 < K; k0 += 64) {
        __syncthreads();
        #pragma unroll
        for (int a = 0; a < 2; ++a) {
            int rr = (w << 4) + (a << 3) + (lane >> 3);
            int cc = (lane & 7) ^ (lane >> 3);
            gload_lds16(A + (size_t)(rowBase + rr) * K + k0 + cc * 8,
                        As + (((w << 4) + (a << 3)) << 6));
            gload_lds16(Bt + (size_t)(colBase + rr) * K + k0 + cc * 8,
                        Bs + (((w << 4) + (a << 3)) << 6));
        }
        asm volatile("s_waitcnt vmcnt(0)" ::: "memory");
        __syncthreads();
        short8 af[2][2], bf[2][2];
        #pragma unroll
        for (int m = 0; m < 2; ++m) {
            af[m][0] = *frg(As, wr * 32 + m * 16 + l15, lg);
            af[m][1] = *frg(As, wr * 32 + m * 16 + l15, 4 + lg);
        }
        #pragma unroll
        for (int n = 0; n < 2; ++n) {
            bf[n][0] = *frg(Bs, wc * 32 + n * 16 + l15, lg);
            bf[n][1] = *frg(Bs, wc * 32 + n * 16 + l15, 4 + lg);
        }
        #pragma unroll
        for (int m = 0; m < 2; ++m)
            #pragma unroll
            for (int n = 0; n < 2; ++n) {
                acc[m][n] = __builtin_amdgcn_mfma_f32_16x16x32_bf16(af[m][0], bf[n][0], acc[m][n], 0, 0, 0);
                acc[m][n] = __builtin_amdgcn_mfma_f32_16x16x32_bf16(af[m][1], bf[n][1], acc[m][n], 0, 0, 0);
            }
    }

    int arB = rowBase + wr * 32;
    int brB = colBase + wc * 32;
    if (z < 2) {
        unsigned short* Out = z ? Kb : Qb;
        #pragma unroll
        for (int m = 0; m < 2; ++m)
            #pragma unroll
            for (int i = 0; i < 4; ++i) {
                int ar = arB + m * 16 + lg * 4 + i;
                #pragma unroll
                for (int n = 0; n < 2; ++n)
                    Out[(size_t)ar * IN_ + brB + n * 16 + l15] = f2bf(acc[m][n][i]);
            }
    } else {
        int bb = brB / N_;
        #pragma unroll
        for (int m = 0; m < 2; ++m)
            #pragma unroll
            for (int i = 0; i < 4; ++i) {
                int ar = arB + m * 16 + lg * 4 + i;
                #pragma unroll
                for (int n = 0; n < 2; ++n) {
                    int br = brB + n * 16 + l15;
                    Vt[((size_t)(bb * IN_) + ar) * N_ + (br - bb * N_)] = f2bf(acc[m][n][i]);
                }
            }
    }
}

// ---------------------------------------------------------------------------
// MFMA flash attention, 2-way KV split, in-register P, shift-free softmax,
// l via ones-MFMA, gload_lds dbuf staging (round-28 proven shell).
// ROUND 29 (session best, restored): intra-wave pipe interleave — tile body
// QK0||QK1 -> SM0 -> PV(kk=0,1) -> SM1 -> PV(kk=2,3). Bit-identical math.
// (Round 30's 2-q-tile ILP variant regressed: 576 blocks vs 2-block cap =
// residency tail; VGPR 68->116; waves are the latency-hiding currency here.)
__global__ __launch_bounds__(256, 3)
void k_flash_mfma(const short* __restrict__ Qb, const short* __restrict__ Kb,
                  const short* __restrict__ Vt,
                  unsigned short* O0, unsigned short* O1,
                  float* __restrict__ Lsum) {
    __shared__ __align__(16) short Ks[2][64 * 64];   // [kv][d] swizzled (swz2)
    __shared__ __align__(16) short Vs[2][64 * 64];   // [d][kv] swizzled (swz2)
    int tid = threadIdx.x;
    int lane = tid & 63;
    int l31 = lane & 31;
    int h5 = lane >> 5;         // 0/1
    int w = tid >> 6;

    int logical = (blockIdx.x & 7) * 144 + (blockIdx.x >> 3);
    int pair = logical / 18;            // (half<<5) | bh, pair in [0,64)
    int qi = logical - pair * 18;
    int bh = pair & 31;
    int half = pair >> 5;
    int bb = bh >> 3, h = bh & 7;
    int qBase = qi * 128;
    int h0 = half * NHALF;

    const short* Qp = Qb + ((size_t)bb * N_ + qBase + w * 32) * IN_ + h * DH_;
    const short* Kp = Kb + (size_t)bb * N_ * IN_ + h * DH_;
    const short* Vp = Vt + ((size_t)bb * IN_ + h * DH_) * N_;

    // Q fragments (B-operand, col q = l31, k = kk*16 + h5*8 + j), from global
    short8 qf[4];
    #pragma unroll
    for (int kk = 0; kk < 4; ++kk)
        qf[kk] = *(const short8*)(Qp + (size_t)l31 * IN_ + kk * 16 + h5 * 8);

    // bf16 ones fragment for the l-accumulating MFMA
    short8 ones;
    #pragma unroll
    for (int j = 0; j < 8; ++j) ones[j] = (short)0x3F80;

    auto STAGE = [&](int buf, int kt2) {
        #pragma unroll
        for (int j = 0; j < 2; ++j) {
            int br = (w << 4) + (j << 3);
            int rr = br + (lane >> 3);
            int cc = (lane & 7) ^ (lane >> 3) ^ ((2 * w + j) & 3);
            gload_lds16(Kp + (size_t)(kt2 + rr) * IN_ + cc * 8, &Ks[buf][br << 6]);
            gload_lds16(Vp + (size_t)rr * N_ + kt2 + cc * 8, &Vs[buf][br << 6]);
        }
    };

    // softmax+pack for one subtile's stv -> two A-fragments (pa_lo, pa_hi)
    auto SMPACK = [&](const f32x16& stv, short8& paLo, short8& paHi) {
        unsigned u[8];
        #pragma unroll
        for (int q = 0; q < 4; ++q) {
            u[2 * q]     = cvtpk(fexp2(stv[4 * q + 0]), fexp2(stv[4 * q + 1]));
            u[2 * q + 1] = cvtpk(fexp2(stv[4 * q + 2]), fexp2(stv[4 * q + 3]));
        }
        asm volatile("v_permlane32_swap_b32 %0, %1" : "+v"(u[0]), "+v"(u[2]));
        asm volatile("v_permlane32_swap_b32 %0, %1" : "+v"(u[1]), "+v"(u[3]));
        asm volatile("v_permlane32_swap_b32 %0, %1" : "+v"(u[4]), "+v"(u[6]));
        asm volatile("v_permlane32_swap_b32 %0, %1" : "+v"(u[5]), "+v"(u[7]));
        union { unsigned uu[4]; short8 s8; } c0, c1;
        c0.uu[0] = u[0]; c0.uu[1] = u[1]; c0.uu[2] = u[2]; c0.uu[3] = u[3];
        c1.uu[0] = u[4]; c1.uu[1] = u[5]; c1.uu[2] = u[6]; c1.uu[3] = u[7];
        paLo = c0.s8;
        paHi = c1.s8;
    };

    f32x16 oacc0 = (f32x16)(0.0f);
    f32x16 oacc1 = (f32x16)(0.0f);
    f32x16 lacc  = (f32x16)(0.0f);

    STAGE(0, h0);
    const int NT = NHALF / 64;   // 18 tiles
    for (int t = 0; t < NT; ++t) {
        asm volatile("s_waitcnt vmcnt(0)" ::: "memory");  // tile t landed
        __builtin_amdgcn_s_barrier();                     // all waves' loads in
        __builtin_amdgcn_sched_barrier(0);                // pin ds_reads after
        if (t + 1 < NT) STAGE((t + 1) & 1, h0 + (t + 1) * 64);  // fly over compute
        const short* Kc = Ks[t & 1];
        const short* Vc = Vs[t & 1];

        // --- QK^T for BOTH kv-subtiles back-to-back (fills matrix pipe) ---
        f32x16 stv0 = (f32x16)(0.0f);
        f32x16 stv1 = (f32x16)(0.0f);
        __builtin_amdgcn_s_setprio(1);
        #pragma unroll
        for (int kk = 0; kk < 4; ++kk) {
            short8 kf = *frg2(Kc, l31, kk * 2 + h5);
            stv0 = __builtin_amdgcn_mfma_f32_32x32x16_bf16(kf, qf[kk], stv0, 0, 0, 0);
        }
        #pragma unroll
        for (int kk = 0; kk < 4; ++kk) {
            short8 kf = *frg2(Kc, 32 + l31, kk * 2 + h5);
            stv1 = __builtin_amdgcn_mfma_f32_32x32x16_bf16(kf, qf[kk], stv1, 0, 0, 0);
        }
        __builtin_amdgcn_s_setprio(0);

        // --- SM0 (stv0 drained during QK1) ---
        short8 pa0, pa1, pa2, pa3;
        SMPACK(stv0, pa0, pa1);

        // --- PV first half (kv 0..31): only needs pa0/pa1 ---
        __builtin_amdgcn_s_setprio(1);
        {
            short8 vf0 = *frg2(Vc, l31, 0 * 2 + h5);
            short8 vg0 = *frg2(Vc, 32 + l31, 0 * 2 + h5);
            lacc  = __builtin_amdgcn_mfma_f32_32x32x16_bf16(pa0, ones, lacc, 0, 0, 0);
            oacc0 = __builtin_amdgcn_mfma_f32_32x32x16_bf16(pa0, vf0, oacc0, 0, 0, 0);
            oacc1 = __builtin_amdgcn_mfma_f32_32x32x16_bf16(pa0, vg0, oacc1, 0, 0, 0);
            short8 vf1 = *frg2(Vc, l31, 1 * 2 + h5);
            short8 vg1 = *frg2(Vc, 32 + l31, 1 * 2 + h5);
            lacc  = __builtin_amdgcn_mfma_f32_32x32x16_bf16(pa1, ones, lacc, 0, 0, 0);
            oacc0 = __builtin_amdgcn_mfma_f32_32x32x16_bf16(pa1, vf1, oacc0, 0, 0, 0);
            oacc1 = __builtin_amdgcn_mfma_f32_32x32x16_bf16(pa1, vg1, oacc1, 0, 0, 0);
        }
        __builtin_amdgcn_s_setprio(0);

        // --- SM1 executes on VALU/TRANS while PV01's MFMAs drain ---
        SMPACK(stv1, pa2, pa3);

        // --- PV second half (kv 32..63) ---
        __builtin_amdgcn_s_setprio(1);
        {
            short8 vf2 = *frg2(Vc, l31, 2 * 2 + h5);
            short8 vg2 = *frg2(Vc, 32 + l31, 2 * 2 + h5);
            lacc  = __builtin_amdgcn_mfma_f32_32x32x16_bf16(pa2, ones, lacc, 0, 0, 0);
            oacc0 = __builtin_amdgcn_mfma_f32_32x32x16_bf16(pa2, vf2, oacc0, 0, 0, 0);
            oacc1 = __builtin_amdgcn_mfma_f32_32x32x16_bf16(pa2, vg2, oacc1, 0, 0, 0);
            short8 vf3 = *frg2(Vc, l31, 3 * 2 + h5);
            short8 vg3 = *frg2(Vc, 32 + l31, 3 * 2 + h5);
            lacc  = __builtin_amdgcn_mfma_f32_32x32x16_bf16(pa3, ones, lacc, 0, 0, 0);
            oacc0 = __builtin_amdgcn_mfma_f32_32x32x16_bf16(pa3, vf3, oacc0, 0, 0, 0);
            oacc1 = __builtin_amdgcn_mfma_f32_32x32x16_bf16(pa3, vg3, oacc1, 0, 0, 0);
        }
        __builtin_amdgcn_s_setprio(0);
    }

    // store UNNORMALIZED bf16 partial; C/D row q = (reg&3)+8*(reg>>2)+4*h5
    unsigned short* OpH = (half == 0) ? O0 : O1;
    unsigned short* Op = OpH + ((size_t)bb * N_ + qBase + w * 32) * IN_ + h * DH_;
    #pragma unroll
    for (int reg = 0; reg < 16; ++reg) {
        int q = (reg & 3) + 8 * (reg >> 2) + 4 * h5;
        Op[(size_t)q * IN_ + l31]      = f2bf(oacc0[reg]);
        Op[(size_t)q * IN_ + 32 + l31] = f2bf(oacc1[reg]);
    }
    if (l31 == 0) {
        float* Lp = Lsum + (((size_t)half * B_ + bb) * H_ + h) * N_ + qBase + w * 32;
        #pragma unroll
        for (int reg = 0; reg < 16; ++reg) {
            int q = (reg & 3) + 8 * (reg >> 2) + 4 * h5;
            Lp[q] = lacc[reg];
        }
    }
}

// ---------------------------------------------------------------------------
// Combine the 2 KV-half partials: O = (O0+O1) / (l0+l1).
// NOTE: Ob aliases p1's buffer — each thread reads both partials for its
// row/lanes before writing the identical addresses, so this is race-free.
__global__ __launch_bounds__(256)
void k_combine(const unsigned short* p0, const unsigned short* p1,
               const float* __restrict__ Lsum, unsigned short* Ob) {
    int wv = threadIdx.x >> 6;
    int lane = threadIdx.x & 63;
    int row = blockIdx.x * 4 + wv;      // bb*N_ + n
    int bb = row / N_;
    int n = row - bb * N_;
    int hh = lane >> 3;
    float l0 = Lsum[(((size_t)0 * B_ + bb) * H_ + hh) * N_ + n];
    float l1 = Lsum[(((size_t)1 * B_ + bb) * H_ + hh) * N_ + n];
    float inv = 1.0f / (l0 + l1);
    size_t off = (size_t)row * IN_ + lane * 8;
    short8 a0 = *(const short8*)(p0 + off);
    short8 a1 = *(const short8*)(p1 + off);
    unsigned short o[8];
    #pragma unroll
    for (int j = 0; j < 8; ++j)
        o[j] = f2bf((bf2f((unsigned short)a0[j]) + bf2f((unsigned short)a1[j])) * inv);
    *(uint4*)(Ob + off) = *(uint4*)o;
}

// ---------------------------------------------------------------------------
extern "C" void kernel_launch(void* const* d_in, const int* in_sizes, int n_in,
                              void* d_out, int out_size, void* d_ws, size_t ws_size,
                              hipStream_t stream) {
    (void)in_sizes; (void)n_in; (void)out_size; (void)ws_size;
    const float* x   = (const float*)d_in[0];
    const float* Wq  = (const float*)d_in[1];
    const float* Wk  = (const float*)d_in[2];
    const float* Wv  = (const float*)d_in[3];
    const float* Wo  = (const float*)d_in[4];
    const float* bo  = (const float*)d_in[5];
    const float* g1  = (const float*)d_in[6];
    const float* b1  = (const float*)d_in[7];
    const float* g2  = (const float*)d_in[8];
    const float* b2  = (const float*)d_in[9];
    const float* Wf1 = (const float*)d_in[10];
    const float* bf1 = (const float*)d_in[11];
    const float* Wf2 = (const float*)d_in[12];
    const float* bf2 = (const float*)d_in[13];
    const float* Wp  = (const float*)d_in[14];
    const float* bp  = (const float*)d_in[15];
    float* out = (float*)d_out;
    float* ws  = (float*)d_ws;

    float* T    = ws;                                  // [9216,256] f32
    float* T2   = ws + 2359296;                        // [9216,256] f32
    unsigned short* TNh = (unsigned short*)(ws + 4718592);   // [9216,256] bf16
    short* Qb   = (short*)(ws + 5898240);              // [9216,512] bf16
    short* Kb   = (short*)(ws + 8257536);              // [9216,512] bf16
    short* Vt   = (short*)(ws + 10616832);             // [4,512,2304] bf16
    unsigned short* Obh = (unsigned short*)(ws + 12976128); // [9216,512] bf16 (= partial 1)
    short* F    = (short*)(ws + 15335424);             // [9216,512] bf16
    short* T3h  = (short*)(ws + 17694720);             // [9216,256] bf16
    unsigned short* Wqh  = (unsigned short*)(ws + 18874368);
    unsigned short* Wkh  = (unsigned short*)(ws + 18939904);
    unsigned short* Wvh  = (unsigned short*)(ws + 19005440);
    unsigned short* Woh  = (unsigned short*)(ws + 19070976);
    unsigned short* Wf1h = (unsigned short*)(ws + 19136512);
    unsigned short* Wf2h = (unsigned short*)(ws + 19202048);
    unsigned short* Wph  = (unsigned short*)(ws + 19267584);
    unsigned short* Op0  = (unsigned short*)(ws + 19398656); // [9216,512] bf16
    unsigned short* Op1  = Obh;                               // aliased (safe)
    float* Lsum = ws + 24117248;                       // [2,4,8,2304] f32

    k_pre<<<dim3(2080), 256, 0, stream>>>(Wq, Wk, Wv, Wo, Wf1, Wf2, Wp,
                                          Wqh, Wkh, Wvh, Woh, Wf1h, Wf2h, Wph,
                                          x, T, TNh, g1, b1);
    k_gemm_qkv<<<dim3(3456), 256, 0, stream>>>((const short*)TNh, (const short*)Wqh,
                                               (const short*)Wkh, (const short*)Wvh,
                                               (unsigned short*)Qb, (unsigned short*)Kb,
                                               (unsigned short*)Vt);
    k_flash_mfma<<<dim3(1152), 256, 0, stream>>>(Qb, Kb, Vt, Op0, Op1, Lsum);
    k_combine<<<2304, 256, 0, stream>>>(Op0, Op1, Lsum, Obh);
    k_gemm64<2><<<dim3(4, 144), 256, 0, stream>>>((const short*)Obh, (const short*)Woh, T2, bo, T, ROWS_, C_, IN_);
    k_layernorm_bf16<<<2304, 256, 0, stream>>>(T2, TNh, g2, b2);
    k_gemm64<3><<<dim3(8, 144), 256, 0, stream>>>((const short*)TNh, (const short*)Wf1h, F, bf1, nullptr, ROWS_, IN_, C_);
    k_gemm64<4><<<dim3(4, 144), 256, 0, stream>>>((const short*)F, (const short*)Wf2h, T3h, bf2, T2, ROWS_, C_, IN_);
    k_gemm64<5><<<dim3(144, 4), 256, 0, stream>>>((const short*)Wph, (const short*)T3h, out, bp, x, C_, ROWS_, C_);
}